// Round 7
// baseline (395.511 us; speedup 1.0000x reference)
//
#include <hip/hip_runtime.h>
#include <hip/hip_bf16.h>
#include <cstdint>

#define TT 300
#define NB 8

static constexpr float D_SR  = 0.90483741803595957f;   // exp(-1/10)
static constexpr float B_SR  = 0.27182818284590454f;   // e/10
static constexpr float D_RF  = 0.36787944117144233f;   // exp(-1)
static constexpr float A_RF  = -54.365636569180902f;   // -2*theta*e
static constexpr float THETA_F = 10.0f;
static constexpr float PGAIN = 11.0f;                  // 1.1*theta

typedef const float __attribute__((address_space(4)))* cfp;  // constant AS -> s_load

// ---- weight transpose: [oc][s] -> [s][oc]
__global__ void k_wtr(const float* __restrict__ w1, const float* __restrict__ w2,
                      const float* __restrict__ w3, float* __restrict__ t1,
                      float* __restrict__ t2, float* __restrict__ t3) {
    int g = blockIdx.x * blockDim.x + threadIdx.x;
    if (g < 400) {                       // conv1: 16 oc x 25
        int oc = g / 25, s = g % 25;
        t1[s * 16 + oc] = w1[g];
    } else if (g < 400 + 4608) {         // conv2: 32 oc x 144
        int h = g - 400, oc = h / 144, s = h % 144;
        t2[s * 32 + oc] = w2[h];
    } else if (g < 400 + 4608 + 18432) { // conv3: 64 oc x 288
        int h = g - 5008, oc = h / 288, s = h % 288;
        t3[s * 64 + oc] = w3[h];
    }
}

// ---- psp on input + transpose  in:[NS][T] -> out:[T][NS]
__global__ void k_psp_tr(const float* __restrict__ in, float* __restrict__ out, int NS) {
    int i = blockIdx.x * blockDim.x + threadIdx.x;
    if (i >= NS) return;
    const float4* x4 = (const float4*)(in + (size_t)i * TT);
    constexpr int G4 = 5, NG = TT / (4 * G4);
    float4 Aa[G4], Bb[G4];
    #pragma unroll
    for (int u = 0; u < G4; ++u) Aa[u] = x4[u];
    float p = 0.f, q = 0.f;
    for (int g = 0; g < NG; ++g) {
        if (g + 1 < NG) {
            #pragma unroll
            for (int u = 0; u < G4; ++u) Bb[u] = x4[(g + 1) * G4 + u];
        }
        int t0 = g * G4 * 4;
        #pragma unroll
        for (int u = 0; u < G4; ++u) {
            float xs[4] = {Aa[u].x, Aa[u].y, Aa[u].z, Aa[u].w};
            #pragma unroll
            for (int e = 0; e < 4; ++e) {
                q = D_SR * (q + p);
                p = D_SR * p + xs[e];
                out[(size_t)(t0 + u * 4 + e) * NS + i] = B_SR * q;
            }
        }
        #pragma unroll
        for (int u = 0; u < G4; ++u) Aa[u] = Bb[u];
    }
}

// ---- tiled conv (conv1 only now): one WG per (t,n); LDS-padded input; scalar weights
template<int CI, int CO, int KS, int HI, int WI, int HO, int WO, int OCW, int J>
__global__ __launch_bounds__(256) void k_conv(const float* __restrict__ in,
                                              const float* __restrict__ wT,
                                              float* __restrict__ out) {
    constexpr int PW = WI + 2, PH = HI + 2, PST = PH * PW;
    __shared__ float lds[CI * PST];
    const int tid = threadIdx.x;
    const int tn  = blockIdx.x;
    cfp wc = (cfp)(uintptr_t)wT;
    const float* img = in + (size_t)tn * (CI * HI * WI);
    for (int idx = tid; idx < CI * PST; idx += 256) lds[idx] = 0.f;
    __syncthreads();
    for (int idx = tid; idx < CI * HI * WI; idx += 256) {
        int ic = idx / (HI * WI), rem = idx % (HI * WI);
        int r = rem / WI, c = rem % WI;
        lds[ic * PST + (r + 1) * PW + (c + 1)] = img[idx];
    }
    __syncthreads();

    const int wave = __builtin_amdgcn_readfirstlane(tid >> 6);
    const int lane = tid & 63;
    const int l = lane < 49 ? lane : 48;
    const int oc0 = (CO == OCW) ? 0 : wave * OCW;

    int pbase[J];
    #pragma unroll
    for (int j = 0; j < J; ++j) {
        int g = (CO == OCW) ? (wave * J + j) : j;
        int px = g * 49 + l;
        pbase[j] = (px / WO) * PW + (px % WO);
    }
    float acc[J * OCW];
    #pragma unroll
    for (int a = 0; a < J * OCW; ++a) acc[a] = 0.f;

    for (int ic = 0; ic < CI; ++ic) {
        #pragma unroll
        for (int kh = 0; kh < KS; ++kh) {
            #pragma unroll
            for (int kw = 0; kw < KS; ++kw) {
                const int step = (ic * KS + kh) * KS + kw;
                float iv[J];
                #pragma unroll
                for (int j = 0; j < J; ++j)
                    iv[j] = lds[ic * PST + pbase[j] + kh * PW + kw];
                #pragma unroll
                for (int o = 0; o < OCW; ++o) {
                    float wv = wc[(size_t)step * CO + oc0 + o];  // uniform -> SGPR
                    #pragma unroll
                    for (int j = 0; j < J; ++j) acc[j * OCW + o] += iv[j] * wv;
                }
            }
        }
    }
    if (lane < 49) {
        #pragma unroll
        for (int j = 0; j < J; ++j) {
            int g = (CO == OCW) ? (wave * J + j) : j;
            int px = g * 49 + lane;
            #pragma unroll
            for (int o = 0; o < OCW; ++o)
                out[((size_t)tn * CO + oc0 + o) * (HO * WO) + px] = acc[j * OCW + o];
        }
    }
}

// ---- conv2 v2: 2 images/block; lane = (img-half, oc); 4 waves = row-quartiles.
// Per-acc order ic -> kh (ir asc) -> kw; edge pads skipped (exact +0).
template<int R0, int R1>
__device__ __forceinline__ void conv2_acc(const float* __restrict__ ib,
                                          const float* __restrict__ wp,
                                          float* __restrict__ acc) {
    #pragma unroll
    for (int a = 0; a < (R1 - R0) * 14; ++a) acc[a] = 0.f;
    for (int ic = 0; ic < 16; ++ic) {
        float w[9];
        #pragma unroll
        for (int s = 0; s < 9; ++s) w[s] = wp[(ic * 9 + s) * 32];
        constexpr int IR0 = (R0 == 0) ? 0 : R0 - 1;
        constexpr int IR1 = (R1 == 14) ? 13 : R1;
        #pragma unroll
        for (int ir = IR0; ir <= IR1; ++ir) {
            const float4* rp = (const float4*)(ib + ic * 224 + ir * 16);
            float4 a4 = rp[0], b4 = rp[1], c4 = rp[2], d4 = rp[3];
            float row[14] = {a4.x, a4.y, a4.z, a4.w, b4.x, b4.y, b4.z, b4.w,
                             c4.x, c4.y, c4.z, c4.w, d4.x, d4.y};
            #pragma unroll
            for (int kh = 0; kh < 3; ++kh) {
                const int r = ir + 1 - kh;
                if (r < R0 || r >= R1) continue;
                #pragma unroll
                for (int c = 0; c < 14; ++c) {
                    #pragma unroll
                    for (int kw = 0; kw < 3; ++kw) {
                        const int jc = c + kw - 1;
                        if (jc < 0 || jc >= 14) continue;
                        acc[(r - R0) * 14 + c] += row[jc] * w[kh * 3 + kw];
                    }
                }
            }
        }
    }
}

__global__ __launch_bounds__(256) void k_conv2(const float* __restrict__ in,
                                               const float* __restrict__ wT,
                                               float* __restrict__ out) {
    __shared__ float lds[7168];                    // stage [2][16][14][16]; reuse as T[2][32][99]
    const int tid = threadIdx.x;
    const int tn0 = blockIdx.x * 2;
    const float* src = in + (size_t)tn0 * 3136;
    for (int idx = tid; idx < 6272; idx += 256) {
        int img = idx / 3136, rem = idx % 3136;
        int ic = rem / 196, k = rem % 196;
        int r = k / 14, c = k % 14;
        lds[img * 3584 + ic * 224 + r * 16 + c] = src[idx];
    }
    __syncthreads();
    const int wave = __builtin_amdgcn_readfirstlane(tid >> 6);
    const int lane = tid & 63;
    const int imgh = lane >> 5;
    const int oc   = lane & 31;
    const float* ib = lds + imgh * 3584;
    const float* wp = wT + oc;                     // [144][32]
    float acc[56];
    if      (wave == 0) conv2_acc<0, 4 >(ib, wp, acc);
    else if (wave == 1) conv2_acc<4, 7 >(ib, wp, acc);
    else if (wave == 2) conv2_acc<7, 11>(ib, wp, acc);
    else                conv2_acc<11, 14>(ib, wp, acc);
    __syncthreads();                               // staging dead; reuse LDS as T
    const int tb = (imgh * 32 + oc) * 99;          // stride 99: conflict-free
    // pass 1: rows 0..6 -> px 0..97
    if (wave == 0) {
        #pragma unroll
        for (int j = 0; j < 56; ++j) lds[tb + j] = acc[j];
    } else if (wave == 1) {
        #pragma unroll
        for (int j = 0; j < 42; ++j) lds[tb + 56 + j] = acc[j];
    }
    __syncthreads();
    for (int idx = tid; idx < 6272; idx += 256) {
        int img = idx / 3136, rem = idx % 3136, o = rem / 98, px = rem % 98;
        out[((size_t)(tn0 + img) * 32 + o) * 196 + px] = lds[(img * 32 + o) * 99 + px];
    }
    __syncthreads();
    // pass 2: rows 7..13 -> px 98..195
    if (wave == 2) {
        #pragma unroll
        for (int j = 0; j < 56; ++j) lds[tb + j] = acc[j];
    } else if (wave == 3) {
        #pragma unroll
        for (int j = 0; j < 42; ++j) lds[tb + 56 + j] = acc[j];
    }
    __syncthreads();
    for (int idx = tid; idx < 6272; idx += 256) {
        int img = idx / 3136, rem = idx % 3136, o = rem / 98, px = rem % 98;
        out[((size_t)(tn0 + img) * 32 + o) * 196 + 98 + px] = lds[(img * 32 + o) * 99 + px];
    }
}

// ---- conv3 v2 (R5 measured-best): lane=oc, image in LDS, 2 waves split px rows.
template<int RB, int RE, int IRB, int IRE>
__device__ __forceinline__ void conv3_rows(const float* lds, const float* wp,
                                           float* __restrict__ out, int tn, int lane) {
    constexpr int NR = RE - RB;
    float acc[NR * 7];
    #pragma unroll
    for (int a = 0; a < NR * 7; ++a) acc[a] = 0.f;
    for (int ic = 0; ic < 32; ++ic) {
        float w[9];
        #pragma unroll
        for (int s = 0; s < 9; ++s) w[s] = wp[(ic * 9 + s) * 64];  // coalesced VMEM
        #pragma unroll
        for (int ir = IRB; ir < IRE; ++ir) {
            float row[7];
            #pragma unroll
            for (int c = 0; c < 7; ++c) row[c] = lds[ic * 49 + ir * 7 + c];  // broadcast
            #pragma unroll
            for (int kh = 0; kh < 3; ++kh) {
                const int r = ir + 1 - kh;
                if (r < RB || r >= RE) continue;
                #pragma unroll
                for (int c = 0; c < 7; ++c) {
                    #pragma unroll
                    for (int kw = 0; kw < 3; ++kw) {
                        const int jc = c + kw - 1;
                        if (jc < 0 || jc >= 7) continue;
                        acc[(r - RB) * 7 + c] += row[jc] * w[kh * 3 + kw];
                    }
                }
            }
        }
    }
    #pragma unroll
    for (int r = RB; r < RE; ++r)
        #pragma unroll
        for (int c = 0; c < 7; ++c)
            out[((size_t)tn * 64 + lane) * 49 + r * 7 + c] = acc[(r - RB) * 7 + c];
}

__global__ __launch_bounds__(128) void k_conv3(const float* __restrict__ in,
                                               const float* __restrict__ wT,
                                               float* __restrict__ out) {
    __shared__ float lds[1568];                        // one [32][7][7] image
    const int tid = threadIdx.x;
    const int tn  = blockIdx.x;
    const float4* src = (const float4*)(in + (size_t)tn * 1568);
    for (int idx = tid; idx < 392; idx += 128) ((float4*)lds)[idx] = src[idx];
    __syncthreads();
    const int lane = tid & 63;
    const float* wp = wT + lane;                       // [step][64]
    if (tid < 64) conv3_rows<0, 4, 0, 5>(lds, wp, out, tn, lane);  // px rows 0..3
    else          conv3_rows<4, 7, 3, 7>(lds, wp, out, tn, lane);  // px rows 4..6
}

// ---- fused spike(x4)->pool->psp->spike->psp (1 thread per pooled neuron)
template<int C, int HI, int WI>
__global__ void k_fuse_pool(const float* __restrict__ U, float* __restrict__ X) {
    constexpr int HO = HI / 2, WO = WI / 2;
    constexpr int M   = NB * C * HO * WO;
    constexpr int NSI = NB * C * HI * WI;
    int i = blockIdx.x * blockDim.x + threadIdx.x;
    if (i >= M) return;
    int j = i % WO, r = (i / WO) % HO, nc = i / (WO * HO);
    size_t base = (size_t)(nc * HI + 2 * r) * WI + 2 * j;
    const float2* R0 = (const float2*)(U + base);
    const float2* R1 = (const float2*)(U + base + WI);
    constexpr int G = 10, NG = TT / G;
    float2 A0[G], A1[G], B0[G], B1[G];
    #pragma unroll
    for (int u = 0; u < G; ++u) {
        A0[u] = R0[(size_t)u * (NSI / 2)];
        A1[u] = R1[(size_t)u * (NSI / 2)];
    }
    float p00=0,q00=0,p01=0,q01=0,p10=0,q10=0,p11=0,q11=0;
    float P=0,Q=0, sp=0,sq=0, P2=0,Q2=0;
    for (int g = 0; g < NG; ++g) {
        if (g + 1 < NG) {
            #pragma unroll
            for (int u = 0; u < G; ++u) {
                B0[u] = R0[(size_t)((g + 1) * G + u) * (NSI / 2)];
                B1[u] = R1[(size_t)((g + 1) * G + u) * (NSI / 2)];
            }
        }
        #pragma unroll
        for (int u = 0; u < G; ++u) {
            int t = g * G + u;
            float s0, s1, s2, s3;
            q00 = D_RF*(q00+p00); { float v = A0[u].x + A_RF*q00; s0 = (v>=THETA_F)?1.f:0.f; } p00 = D_RF*p00+s0;
            q01 = D_RF*(q01+p01); { float v = A0[u].y + A_RF*q01; s1 = (v>=THETA_F)?1.f:0.f; } p01 = D_RF*p01+s1;
            q10 = D_RF*(q10+p10); { float v = A1[u].x + A_RF*q10; s2 = (v>=THETA_F)?1.f:0.f; } p10 = D_RF*p10+s2;
            q11 = D_RF*(q11+p11); { float v = A1[u].y + A_RF*q11; s3 = (v>=THETA_F)?1.f:0.f; } p11 = D_RF*p11+s3;
            float x = (s0 + s1 + s2 + s3) * PGAIN;
            Q = D_SR*(Q+P); P = D_SR*P + x; float drive = B_SR*Q;
            sq = D_RF*(sq+sp); float v2 = drive + A_RF*sq; float sv = (v2>=THETA_F)?1.f:0.f; sp = D_RF*sp+sv;
            Q2 = D_SR*(Q2+P2); P2 = D_SR*P2 + sv;
            X[(size_t)t * M + i] = B_SR * Q2;
        }
        #pragma unroll
        for (int u = 0; u < G; ++u) { A0[u] = B0[u]; A1[u] = B1[u]; }
    }
}

// ---- fused spike -> psp, out-of-place, prefetched
__global__ void k_spike_psp(const float* __restrict__ U, float* __restrict__ X, int NS) {
    int i = blockIdx.x * blockDim.x + threadIdx.x;
    if (i >= NS) return;
    constexpr int G = 20, NG = TT / G;
    float Aa[G], Bb[G];
    #pragma unroll
    for (int u = 0; u < G; ++u) Aa[u] = U[(size_t)u * NS + i];
    float p = 0, q = 0, P = 0, Q = 0;
    for (int g = 0; g < NG; ++g) {
        if (g + 1 < NG) {
            #pragma unroll
            for (int u = 0; u < G; ++u) Bb[u] = U[(size_t)((g + 1) * G + u) * NS + i];
        }
        #pragma unroll
        for (int u = 0; u < G; ++u) {
            int t = g * G + u;
            q = D_RF * (q + p);
            float v = Aa[u] + A_RF * q;
            float s = (v >= THETA_F) ? 1.f : 0.f;
            p = D_RF * p + s;
            Q = D_SR * (Q + P); P = D_SR * P + s;
            X[(size_t)t * NS + i] = B_SR * Q;
        }
        #pragma unroll
        for (int u = 0; u < G; ++u) Aa[u] = Bb[u];
    }
}

// ---- dense: one wave per (t,n)
__global__ void k_dense(const float* __restrict__ X, const float* __restrict__ wf,
                        float* __restrict__ G_) {
    int tn = blockIdx.x;
    int lane = threadIdx.x;
    const float* xb = X + (size_t)tn * 3136;
    float acc[10];
    #pragma unroll
    for (int o = 0; o < 10; ++o) acc[o] = 0.f;
    for (int it = 0; it < 49; ++it) {
        int k = it * 64 + lane;
        float xv = xb[k];
        #pragma unroll
        for (int o = 0; o < 10; ++o) acc[o] += xv * wf[o * 3136 + k];
    }
    #pragma unroll
    for (int off = 32; off > 0; off >>= 1) {
        #pragma unroll
        for (int o = 0; o < 10; ++o) acc[o] += __shfl_down(acc[o], off);
    }
    if (lane == 0) {
        #pragma unroll
        for (int o = 0; o < 10; ++o) G_[tn * 10 + o] = acc[o];
    }
}

// ---- final spike on [T][80] -> out [N][10][T]
__global__ void k_spike_out(const float* __restrict__ G_, float* __restrict__ out) {
    int i = threadIdx.x;
    if (i >= 80) return;
    constexpr int G = 20, NG = TT / G;
    float Aa[G], Bb[G];
    #pragma unroll
    for (int u = 0; u < G; ++u) Aa[u] = G_[u * 80 + i];
    float p = 0, q = 0;
    for (int g = 0; g < NG; ++g) {
        if (g + 1 < NG) {
            #pragma unroll
            for (int u = 0; u < G; ++u) Bb[u] = G_[((g + 1) * G + u) * 80 + i];
        }
        #pragma unroll
        for (int u = 0; u < G; ++u) {
            int t = g * G + u;
            q = D_RF * (q + p);
            float v = Aa[u] + A_RF * q;
            float s = (v >= THETA_F) ? 1.f : 0.f;
            p = D_RF * p + s;
            out[(size_t)i * TT + t] = s;
        }
        #pragma unroll
        for (int u = 0; u < G; ++u) Aa[u] = Bb[u];
    }
}

static inline int cdiv(int a, int b) { return (a + b - 1) / b; }

extern "C" void kernel_launch(void* const* d_in, const int* in_sizes, int n_in,
                              void* d_out, int out_size, void* d_ws, size_t ws_size,
                              hipStream_t stream) {
    const float* x  = (const float*)d_in[0];   // [8,1,30,30,300]
    const float* w1 = (const float*)d_in[1];   // [16,1,5,5]
    const float* w2 = (const float*)d_in[2];   // [32,16,3,3]
    const float* w3 = (const float*)d_in[3];   // [64,32,3,3]
    const float* wf = (const float*)d_in[4];   // [10,64,7,7]
    float* out = (float*)d_out;                // [8,10,300]
    float* ws  = (float*)d_ws;

    // workspace (floats)
    float* A   = ws;                    // [300][7200]
    float* U1  = ws + 2160000;          // [300][100352] (120 MB slot)
    float* X2  = ws + 32265600;         // [300][25088]
    float* Gg  = ws + 39792000;         // [300][80]
    float* wT1 = ws + 39816000;         // [25][16]
    float* wT2 = ws + 39816400;         // [144][32]
    float* wT3 = ws + 39821008;         // [288][64]
    // lifetime-disjoint aliases
    float* U2  = U1;                    // [300][50176]
    float* X4  = U1 + 16000000;         // [300][12544]
    float* U3  = X2;                    // [300][25088]
    float* X5  = U1;                    // [300][25088]

    const int B = 256;
    k_wtr<<<cdiv(23440, B), B, 0, stream>>>(w1, w2, w3, wT1, wT2, wT3);
    k_psp_tr<<<cdiv(7200, B), B, 0, stream>>>(x, A, 7200);
    // conv1: 1->16, 5x5 pad1, 30x30 -> 28x28
    k_conv<1, 16, 5, 30, 30, 28, 28, 16, 4><<<2400, B, 0, stream>>>(A, wT1, U1);
    k_fuse_pool<16, 28, 28><<<cdiv(25088, B), B, 0, stream>>>(U1, X2);
    // conv2 v2: 2 images/block, lane=(img,oc), 4 row-quartile waves
    k_conv2<<<1200, B, 0, stream>>>(X2, wT2, U2);
    k_fuse_pool<32, 14, 14><<<cdiv(12544, B), B, 0, stream>>>(U2, X4);
    // conv3 v2: 1 image/block, 2 waves split px rows (R5 measured-best)
    k_conv3<<<2400, 128, 0, stream>>>(X4, wT3, U3);
    k_spike_psp<<<cdiv(25088, B), B, 0, stream>>>(U3, X5, 25088);
    k_dense<<<2400, 64, 0, stream>>>(X5, wf, Gg);
    k_spike_out<<<1, 128, 0, stream>>>(Gg, out);
}

// Round 8
// 387.746 us; speedup vs baseline: 1.0200x; 1.0200x over previous
//
#include <hip/hip_runtime.h>
#include <hip/hip_bf16.h>
#include <cstdint>

#define TT 300
#define NB 8

static constexpr float D_SR  = 0.90483741803595957f;   // exp(-1/10)
static constexpr float B_SR  = 0.27182818284590454f;   // e/10
static constexpr float D_RF  = 0.36787944117144233f;   // exp(-1)
static constexpr float A_RF  = -54.365636569180902f;   // -2*theta*e
static constexpr float THETA_F = 10.0f;
static constexpr float PGAIN = 11.0f;                  // 1.1*theta

typedef const float __attribute__((address_space(4)))* cfp;  // constant AS -> s_load

// ---- weight transpose: [oc][s] -> [s][oc]
__global__ void k_wtr(const float* __restrict__ w1, const float* __restrict__ w2,
                      const float* __restrict__ w3, float* __restrict__ t1,
                      float* __restrict__ t2, float* __restrict__ t3) {
    int g = blockIdx.x * blockDim.x + threadIdx.x;
    if (g < 400) {                       // conv1: 16 oc x 25
        int oc = g / 25, s = g % 25;
        t1[s * 16 + oc] = w1[g];
    } else if (g < 400 + 4608) {         // conv2: 32 oc x 144
        int h = g - 400, oc = h / 144, s = h % 144;
        t2[s * 32 + oc] = w2[h];
    } else if (g < 400 + 4608 + 18432) { // conv3: 64 oc x 288
        int h = g - 5008, oc = h / 288, s = h % 288;
        t3[s * 64 + oc] = w3[h];
    }
}

// ---- psp on input + transpose  in:[NS][T] -> out:[T][NS]
__global__ void k_psp_tr(const float* __restrict__ in, float* __restrict__ out, int NS) {
    int i = blockIdx.x * blockDim.x + threadIdx.x;
    if (i >= NS) return;
    const float4* x4 = (const float4*)(in + (size_t)i * TT);
    constexpr int G4 = 5, NG = TT / (4 * G4);
    float4 Aa[G4], Bb[G4];
    #pragma unroll
    for (int u = 0; u < G4; ++u) Aa[u] = x4[u];
    float p = 0.f, q = 0.f;
    for (int g = 0; g < NG; ++g) {
        if (g + 1 < NG) {
            #pragma unroll
            for (int u = 0; u < G4; ++u) Bb[u] = x4[(g + 1) * G4 + u];
        }
        int t0 = g * G4 * 4;
        #pragma unroll
        for (int u = 0; u < G4; ++u) {
            float xs[4] = {Aa[u].x, Aa[u].y, Aa[u].z, Aa[u].w};
            #pragma unroll
            for (int e = 0; e < 4; ++e) {
                q = D_SR * (q + p);
                p = D_SR * p + xs[e];
                out[(size_t)(t0 + u * 4 + e) * NS + i] = B_SR * q;
            }
        }
        #pragma unroll
        for (int u = 0; u < G4; ++u) Aa[u] = Bb[u];
    }
}

// ---- conv1 v2: 1->16, 5x5 pad1, 30x30 -> 28x28. One block/(t,n), 448 thr,
// lane=(row,oc): zero dead lanes, 16800 waves. Weights in regs; LDS [32][36] padded.
__global__ __launch_bounds__(448) void k_conv1(const float* __restrict__ in,
                                               const float* __restrict__ wT,
                                               float* __restrict__ out) {
    __shared__ float lds[32 * 36];                 // zero-padded image
    const int tid = threadIdx.x;
    const int tn  = blockIdx.x;
    for (int idx = tid; idx < 1152; idx += 448) lds[idx] = 0.f;
    __syncthreads();
    const float* img = in + (size_t)tn * 900;
    for (int idx = tid; idx < 900; idx += 448) {
        int r = idx / 30, c = idx % 30;
        lds[(r + 1) * 36 + (c + 1)] = img[idx];
    }
    __syncthreads();
    const int r  = tid >> 4;                       // output row 0..27
    const int oc = tid & 15;
    float w[25];
    #pragma unroll
    for (int s = 0; s < 25; ++s) w[s] = wT[s * 16 + oc];
    float acc[28];
    #pragma unroll
    for (int c = 0; c < 28; ++c) acc[c] = 0.f;
    #pragma unroll
    for (int kh = 0; kh < 5; ++kh) {
        const float4* rp = (const float4*)(lds + (r + kh) * 36);
        float4 q0 = rp[0], q1 = rp[1], q2 = rp[2], q3 = rp[3],
               q4 = rp[4], q5 = rp[5], q6 = rp[6], q7 = rp[7];
        float row[32] = {q0.x,q0.y,q0.z,q0.w, q1.x,q1.y,q1.z,q1.w,
                         q2.x,q2.y,q2.z,q2.w, q3.x,q3.y,q3.z,q3.w,
                         q4.x,q4.y,q4.z,q4.w, q5.x,q5.y,q5.z,q5.w,
                         q6.x,q6.y,q6.z,q6.w, q7.x,q7.y,q7.z,q7.w};
        #pragma unroll
        for (int kw = 0; kw < 5; ++kw) {
            const float wv = w[kh * 5 + kw];
            #pragma unroll
            for (int c = 0; c < 28; ++c) acc[c] += row[c + kw] * wv;
        }
    }
    float* ob = out + ((size_t)tn * 16 + oc) * 784 + r * 28;
    #pragma unroll
    for (int c4 = 0; c4 < 7; ++c4)
        ((float4*)ob)[c4] = make_float4(acc[c4*4], acc[c4*4+1], acc[c4*4+2], acc[c4*4+3]);
}

// ---- tiled conv (conv2): one WG per (t,n); LDS-padded input; scalar weights
template<int CI, int CO, int KS, int HI, int WI, int HO, int WO, int OCW, int J>
__global__ __launch_bounds__(256) void k_conv(const float* __restrict__ in,
                                              const float* __restrict__ wT,
                                              float* __restrict__ out) {
    constexpr int PW = WI + 2, PH = HI + 2, PST = PH * PW;
    __shared__ float lds[CI * PST];
    const int tid = threadIdx.x;
    const int tn  = blockIdx.x;
    cfp wc = (cfp)(uintptr_t)wT;
    const float* img = in + (size_t)tn * (CI * HI * WI);
    for (int idx = tid; idx < CI * PST; idx += 256) lds[idx] = 0.f;
    __syncthreads();
    for (int idx = tid; idx < CI * HI * WI; idx += 256) {
        int ic = idx / (HI * WI), rem = idx % (HI * WI);
        int r = rem / WI, c = rem % WI;
        lds[ic * PST + (r + 1) * PW + (c + 1)] = img[idx];
    }
    __syncthreads();

    const int wave = __builtin_amdgcn_readfirstlane(tid >> 6);
    const int lane = tid & 63;
    const int l = lane < 49 ? lane : 48;
    const int oc0 = (CO == OCW) ? 0 : wave * OCW;

    int pbase[J];
    #pragma unroll
    for (int j = 0; j < J; ++j) {
        int g = (CO == OCW) ? (wave * J + j) : j;
        int px = g * 49 + l;
        pbase[j] = (px / WO) * PW + (px % WO);
    }
    float acc[J * OCW];
    #pragma unroll
    for (int a = 0; a < J * OCW; ++a) acc[a] = 0.f;

    for (int ic = 0; ic < CI; ++ic) {
        #pragma unroll
        for (int kh = 0; kh < KS; ++kh) {
            #pragma unroll
            for (int kw = 0; kw < KS; ++kw) {
                const int step = (ic * KS + kh) * KS + kw;
                float iv[J];
                #pragma unroll
                for (int j = 0; j < J; ++j)
                    iv[j] = lds[ic * PST + pbase[j] + kh * PW + kw];
                #pragma unroll
                for (int o = 0; o < OCW; ++o) {
                    float wv = wc[(size_t)step * CO + oc0 + o];  // uniform -> SGPR
                    #pragma unroll
                    for (int j = 0; j < J; ++j) acc[j * OCW + o] += iv[j] * wv;
                }
            }
        }
    }
    if (lane < 49) {
        #pragma unroll
        for (int j = 0; j < J; ++j) {
            int g = (CO == OCW) ? (wave * J + j) : j;
            int px = g * 49 + lane;
            #pragma unroll
            for (int o = 0; o < OCW; ++o)
                out[((size_t)tn * CO + oc0 + o) * (HO * WO) + px] = acc[j * OCW + o];
        }
    }
}

// ---- conv3 v2 (R5 measured-best): lane=oc, image in LDS, 2 waves split px rows.
template<int RB, int RE, int IRB, int IRE>
__device__ __forceinline__ void conv3_rows(const float* lds, const float* wp,
                                           float* __restrict__ out, int tn, int lane) {
    constexpr int NR = RE - RB;
    float acc[NR * 7];
    #pragma unroll
    for (int a = 0; a < NR * 7; ++a) acc[a] = 0.f;
    for (int ic = 0; ic < 32; ++ic) {
        float w[9];
        #pragma unroll
        for (int s = 0; s < 9; ++s) w[s] = wp[(ic * 9 + s) * 64];  // coalesced VMEM
        #pragma unroll
        for (int ir = IRB; ir < IRE; ++ir) {
            float row[7];
            #pragma unroll
            for (int c = 0; c < 7; ++c) row[c] = lds[ic * 49 + ir * 7 + c];  // broadcast
            #pragma unroll
            for (int kh = 0; kh < 3; ++kh) {
                const int r = ir + 1 - kh;
                if (r < RB || r >= RE) continue;
                #pragma unroll
                for (int c = 0; c < 7; ++c) {
                    #pragma unroll
                    for (int kw = 0; kw < 3; ++kw) {
                        const int jc = c + kw - 1;
                        if (jc < 0 || jc >= 7) continue;
                        acc[(r - RB) * 7 + c] += row[jc] * w[kh * 3 + kw];
                    }
                }
            }
        }
    }
    #pragma unroll
    for (int r = RB; r < RE; ++r)
        #pragma unroll
        for (int c = 0; c < 7; ++c)
            out[((size_t)tn * 64 + lane) * 49 + r * 7 + c] = acc[(r - RB) * 7 + c];
}

__global__ __launch_bounds__(128) void k_conv3(const float* __restrict__ in,
                                               const float* __restrict__ wT,
                                               float* __restrict__ out) {
    __shared__ float lds[1568];                        // one [32][7][7] image
    const int tid = threadIdx.x;
    const int tn  = blockIdx.x;
    const float4* src = (const float4*)(in + (size_t)tn * 1568);
    for (int idx = tid; idx < 392; idx += 128) ((float4*)lds)[idx] = src[idx];
    __syncthreads();
    const int lane = tid & 63;
    const float* wp = wT + lane;                       // [step][64]
    if (tid < 64) conv3_rows<0, 4, 0, 5>(lds, wp, out, tn, lane);  // px rows 0..3
    else          conv3_rows<4, 7, 3, 7>(lds, wp, out, tn, lane);  // px rows 4..6
}

// ---- fused spike(x4)->pool->psp->spike->psp (1 thread per pooled neuron)
template<int C, int HI, int WI>
__global__ void k_fuse_pool(const float* __restrict__ U, float* __restrict__ X) {
    constexpr int HO = HI / 2, WO = WI / 2;
    constexpr int M   = NB * C * HO * WO;
    constexpr int NSI = NB * C * HI * WI;
    int i = blockIdx.x * blockDim.x + threadIdx.x;
    if (i >= M) return;
    int j = i % WO, r = (i / WO) % HO, nc = i / (WO * HO);
    size_t base = (size_t)(nc * HI + 2 * r) * WI + 2 * j;
    const float2* R0 = (const float2*)(U + base);
    const float2* R1 = (const float2*)(U + base + WI);
    constexpr int G = 10, NG = TT / G;
    float2 A0[G], A1[G], B0[G], B1[G];
    #pragma unroll
    for (int u = 0; u < G; ++u) {
        A0[u] = R0[(size_t)u * (NSI / 2)];
        A1[u] = R1[(size_t)u * (NSI / 2)];
    }
    float p00=0,q00=0,p01=0,q01=0,p10=0,q10=0,p11=0,q11=0;
    float P=0,Q=0, sp=0,sq=0, P2=0,Q2=0;
    for (int g = 0; g < NG; ++g) {
        if (g + 1 < NG) {
            #pragma unroll
            for (int u = 0; u < G; ++u) {
                B0[u] = R0[(size_t)((g + 1) * G + u) * (NSI / 2)];
                B1[u] = R1[(size_t)((g + 1) * G + u) * (NSI / 2)];
            }
        }
        #pragma unroll
        for (int u = 0; u < G; ++u) {
            int t = g * G + u;
            float s0, s1, s2, s3;
            q00 = D_RF*(q00+p00); { float v = A0[u].x + A_RF*q00; s0 = (v>=THETA_F)?1.f:0.f; } p00 = D_RF*p00+s0;
            q01 = D_RF*(q01+p01); { float v = A0[u].y + A_RF*q01; s1 = (v>=THETA_F)?1.f:0.f; } p01 = D_RF*p01+s1;
            q10 = D_RF*(q10+p10); { float v = A1[u].x + A_RF*q10; s2 = (v>=THETA_F)?1.f:0.f; } p10 = D_RF*p10+s2;
            q11 = D_RF*(q11+p11); { float v = A1[u].y + A_RF*q11; s3 = (v>=THETA_F)?1.f:0.f; } p11 = D_RF*p11+s3;
            float x = (s0 + s1 + s2 + s3) * PGAIN;
            Q = D_SR*(Q+P); P = D_SR*P + x; float drive = B_SR*Q;
            sq = D_RF*(sq+sp); float v2 = drive + A_RF*sq; float sv = (v2>=THETA_F)?1.f:0.f; sp = D_RF*sp+sv;
            Q2 = D_SR*(Q2+P2); P2 = D_SR*P2 + sv;
            X[(size_t)t * M + i] = B_SR * Q2;
        }
        #pragma unroll
        for (int u = 0; u < G; ++u) { A0[u] = B0[u]; A1[u] = B1[u]; }
    }
}

// ---- fused spike -> psp, out-of-place, prefetched
__global__ void k_spike_psp(const float* __restrict__ U, float* __restrict__ X, int NS) {
    int i = blockIdx.x * blockDim.x + threadIdx.x;
    if (i >= NS) return;
    constexpr int G = 20, NG = TT / G;
    float Aa[G], Bb[G];
    #pragma unroll
    for (int u = 0; u < G; ++u) Aa[u] = U[(size_t)u * NS + i];
    float p = 0, q = 0, P = 0, Q = 0;
    for (int g = 0; g < NG; ++g) {
        if (g + 1 < NG) {
            #pragma unroll
            for (int u = 0; u < G; ++u) Bb[u] = U[(size_t)((g + 1) * G + u) * NS + i];
        }
        #pragma unroll
        for (int u = 0; u < G; ++u) {
            int t = g * G + u;
            q = D_RF * (q + p);
            float v = Aa[u] + A_RF * q;
            float s = (v >= THETA_F) ? 1.f : 0.f;
            p = D_RF * p + s;
            Q = D_SR * (Q + P); P = D_SR * P + s;
            X[(size_t)t * NS + i] = B_SR * Q;
        }
        #pragma unroll
        for (int u = 0; u < G; ++u) Aa[u] = Bb[u];
    }
}

// ---- dense: one wave per (t,n)
__global__ void k_dense(const float* __restrict__ X, const float* __restrict__ wf,
                        float* __restrict__ G_) {
    int tn = blockIdx.x;
    int lane = threadIdx.x;
    const float* xb = X + (size_t)tn * 3136;
    float acc[10];
    #pragma unroll
    for (int o = 0; o < 10; ++o) acc[o] = 0.f;
    for (int it = 0; it < 49; ++it) {
        int k = it * 64 + lane;
        float xv = xb[k];
        #pragma unroll
        for (int o = 0; o < 10; ++o) acc[o] += xv * wf[o * 3136 + k];
    }
    #pragma unroll
    for (int off = 32; off > 0; off >>= 1) {
        #pragma unroll
        for (int o = 0; o < 10; ++o) acc[o] += __shfl_down(acc[o], off);
    }
    if (lane == 0) {
        #pragma unroll
        for (int o = 0; o < 10; ++o) G_[tn * 10 + o] = acc[o];
    }
}

// ---- final spike on [T][80] -> out [N][10][T]
__global__ void k_spike_out(const float* __restrict__ G_, float* __restrict__ out) {
    int i = threadIdx.x;
    if (i >= 80) return;
    constexpr int G = 20, NG = TT / G;
    float Aa[G], Bb[G];
    #pragma unroll
    for (int u = 0; u < G; ++u) Aa[u] = G_[u * 80 + i];
    float p = 0, q = 0;
    for (int g = 0; g < NG; ++g) {
        if (g + 1 < NG) {
            #pragma unroll
            for (int u = 0; u < G; ++u) Bb[u] = G_[((g + 1) * G + u) * 80 + i];
        }
        #pragma unroll
        for (int u = 0; u < G; ++u) {
            int t = g * G + u;
            q = D_RF * (q + p);
            float v = Aa[u] + A_RF * q;
            float s = (v >= THETA_F) ? 1.f : 0.f;
            p = D_RF * p + s;
            out[(size_t)i * TT + t] = s;
        }
        #pragma unroll
        for (int u = 0; u < G; ++u) Aa[u] = Bb[u];
    }
}

static inline int cdiv(int a, int b) { return (a + b - 1) / b; }

extern "C" void kernel_launch(void* const* d_in, const int* in_sizes, int n_in,
                              void* d_out, int out_size, void* d_ws, size_t ws_size,
                              hipStream_t stream) {
    const float* x  = (const float*)d_in[0];   // [8,1,30,30,300]
    const float* w1 = (const float*)d_in[1];   // [16,1,5,5]
    const float* w2 = (const float*)d_in[2];   // [32,16,3,3]
    const float* w3 = (const float*)d_in[3];   // [64,32,3,3]
    const float* wf = (const float*)d_in[4];   // [10,64,7,7]
    float* out = (float*)d_out;                // [8,10,300]
    float* ws  = (float*)d_ws;

    // workspace (floats)
    float* A   = ws;                    // [300][7200]
    float* U1  = ws + 2160000;          // [300][100352] (120 MB slot)
    float* X2  = ws + 32265600;         // [300][25088]
    float* Gg  = ws + 39792000;         // [300][80]
    float* wT1 = ws + 39816000;         // [25][16]
    float* wT2 = ws + 39816400;         // [144][32]
    float* wT3 = ws + 39821008;         // [288][64]
    // lifetime-disjoint aliases
    float* U2  = U1;                    // [300][50176]
    float* X4  = U1 + 16000000;         // [300][12544]
    float* U3  = X2;                    // [300][25088]
    float* X5  = U1;                    // [300][25088]

    const int B = 256;
    k_wtr<<<cdiv(23440, B), B, 0, stream>>>(w1, w2, w3, wT1, wT2, wT3);
    k_psp_tr<<<cdiv(7200, B), B, 0, stream>>>(x, A, 7200);
    // conv1 v2: lane=(row,oc), weights in regs, float4 stores
    k_conv1<<<2400, 448, 0, stream>>>(A, wT1, U1);
    k_fuse_pool<16, 28, 28><<<cdiv(25088, B), B, 0, stream>>>(U1, X2);
    // conv2 (R5 measured form): 16->32, 3x3 pad1, 14x14
    k_conv<16, 32, 3, 14, 14, 14, 14, 32, 1><<<2400, B, 0, stream>>>(X2, wT2, U2);
    k_fuse_pool<32, 14, 14><<<cdiv(12544, B), B, 0, stream>>>(U2, X4);
    // conv3 v2: 1 image/block, 2 waves split px rows (R5 measured-best)
    k_conv3<<<2400, 128, 0, stream>>>(X4, wT3, U3);
    k_spike_psp<<<cdiv(25088, B), B, 0, stream>>>(U3, X5, 25088);
    k_dense<<<2400, 64, 0, stream>>>(X5, wf, Gg);
    k_spike_out<<<1, 128, 0, stream>>>(Gg, out);
}